// Round 12
// baseline (201.208 us; speedup 1.0000x reference)
//
#include <hip/hip_runtime.h>
#include <math.h>

#define S_TOK 2048
#define H_DIM 1024
#define E_NUM 16
#define FF_DIM 1024
#define TOPK 4
#define CLIPV 7.0f
#define AUXC 0.02f
#define BK 32
#define NT (H_DIM / BK)

typedef short bf16x8 __attribute__((ext_vector_type(8)));
typedef float f32x4 __attribute__((ext_vector_type(4)));

__device__ __forceinline__ unsigned short f2bf(float f) {
  unsigned int u = __float_as_uint(f);
  u += 0x7fffu + ((u >> 16) & 1u);
  return (unsigned short)(u >> 16);
}

__device__ __forceinline__ void gload16(const void* g, void* l) {
  __builtin_amdgcn_global_load_lds((const __attribute__((address_space(1))) void*)g,
                                   (__attribute__((address_space(3))) void*)l, 16, 0, 0);
}

__device__ __forceinline__ int imin(int a, int b) { return a < b ? a : b; }

// ---------------- router logits + x->bf16 convert: one wave per token ----------------
__global__ void logits_kernel(const float* __restrict__ x, const float* __restrict__ rw,
                              const float* __restrict__ rb, float* __restrict__ logits,
                              unsigned short* __restrict__ xb) {
  int tok = blockIdx.x * 4 + (threadIdx.x >> 6);
  int lane = threadIdx.x & 63;
  const float4* xr = (const float4*)(x + (size_t)tok * H_DIM);
  ushort4* xbw = (ushort4*)(xb + (size_t)tok * H_DIM);
  float p[E_NUM];
#pragma unroll
  for (int e = 0; e < E_NUM; ++e) p[e] = 0.f;
#pragma unroll
  for (int it = 0; it < 4; ++it) {
    float4 xv = xr[it * 64 + lane];
    ushort4 o;
    o.x = f2bf(xv.x); o.y = f2bf(xv.y); o.z = f2bf(xv.z); o.w = f2bf(xv.w);
    xbw[it * 64 + lane] = o;
#pragma unroll
    for (int e = 0; e < E_NUM; ++e) {
      float4 wv = ((const float4*)(rw + (size_t)e * H_DIM))[it * 64 + lane];
      p[e] += xv.x * wv.x + xv.y * wv.y + xv.z * wv.z + xv.w * wv.w;
    }
  }
#pragma unroll
  for (int e = 0; e < E_NUM; ++e) {
#pragma unroll
    for (int off = 32; off > 0; off >>= 1) p[e] += __shfl_xor(p[e], off);
  }
  if (lane == 0) {
    float4* lp = (float4*)&logits[tok * E_NUM];
#pragma unroll
    for (int q = 0; q < 4; ++q)
      lp[q] = make_float4(p[q * 4 + 0] + rb[q * 4 + 0], p[q * 4 + 1] + rb[q * 4 + 1],
                          p[q * 4 + 2] + rb[q * 4 + 2], p[q * 4 + 3] + rb[q * 4 + 3]);
  }
}

// ---------------- top-k + aux stats ----------------
__global__ __launch_bounds__(256) void topk_kernel(const float* __restrict__ logits,
                                                   int* __restrict__ topk_i, float* __restrict__ topk_w,
                                                   int* __restrict__ counts, float* __restrict__ imp,
                                                   int* __restrict__ pos_cnt) {
  __shared__ float s_imp[E_NUM];
  __shared__ int s_cnt[E_NUM];
  __shared__ int s_pos[TOPK];
  int tid = threadIdx.x;
  if (tid < E_NUM) { s_imp[tid] = 0.f; s_cnt[tid] = 0; }
  if (tid < TOPK) s_pos[tid] = 0;
  __syncthreads();

  int t = blockIdx.x * 256 + tid;
  float lg[E_NUM];
  {
    const float4* lp = (const float4*)&logits[t * E_NUM];
#pragma unroll
    for (int q = 0; q < 4; ++q) {
      float4 v = lp[q];
      lg[q * 4 + 0] = v.x; lg[q * 4 + 1] = v.y; lg[q * 4 + 2] = v.z; lg[q * 4 + 3] = v.w;
    }
  }
  int idx[TOPK]; float val[TOPK];
  float tmp[E_NUM];
#pragma unroll
  for (int e = 0; e < E_NUM; ++e) tmp[e] = lg[e];
#pragma unroll
  for (int k = 0; k < TOPK; ++k) {
    float best = -INFINITY; int bi = 0;
#pragma unroll
    for (int e = 0; e < E_NUM; ++e) if (tmp[e] > best) { best = tmp[e]; bi = e; }
    val[k] = best; idx[k] = bi; tmp[bi] = -INFINITY;
  }
  float ssum = 0.f, wv[TOPK];
#pragma unroll
  for (int k = 0; k < TOPK; ++k) { wv[k] = expf(val[k] - val[0]); ssum += wv[k]; }
#pragma unroll
  for (int k = 0; k < TOPK; ++k) wv[k] /= ssum;
#pragma unroll
  for (int k = 0; k < TOPK; ++k) {
    topk_i[t * TOPK + k] = idx[k];
    topk_w[t * TOPK + k] = wv[k];
  }
  float se = 0.f, pr[E_NUM];
#pragma unroll
  for (int e = 0; e < E_NUM; ++e) { pr[e] = expf(lg[e] - val[0]); se += pr[e]; }
  float inv = 1.f / se;
  int mi = idx[0], pos = 0;
#pragma unroll
  for (int k = 1; k < TOPK; ++k) if (idx[k] > mi) { mi = idx[k]; pos = k; }

  int lane = tid & 63;
#pragma unroll
  for (int e = 0; e < E_NUM; ++e) {
    float v = pr[e] * inv;
    int c = (idx[0] == e) + (idx[1] == e) + (idx[2] == e) + (idx[3] == e);
#pragma unroll
    for (int off = 32; off > 0; off >>= 1) {
      v += __shfl_xor(v, off);
      c += __shfl_xor(c, off);
    }
    if (lane == 0) {
      atomicAdd(&s_imp[e], v);
      atomicAdd(&s_cnt[e], c);
    }
  }
#pragma unroll
  for (int k = 0; k < TOPK; ++k) {
    int pc = (pos == k) ? 1 : 0;
#pragma unroll
    for (int off = 32; off > 0; off >>= 1) pc += __shfl_xor(pc, off);
    if (lane == 0) atomicAdd(&s_pos[k], pc);
  }
  __syncthreads();
  if (tid < E_NUM) {
    atomicAdd(&imp[tid], s_imp[tid]);
    atomicAdd(&counts[tid], s_cnt[tid]);
  }
  if (tid < TOPK) atomicAdd(&pos_cnt[tid], s_pos[tid]);
}

// ---------------- build grouped token lists + inverse slot map (scan folded in) ----------------
__global__ __launch_bounds__(256) void assign_kernel(
    const int* __restrict__ topk_i, const int* __restrict__ counts, int* __restrict__ cursor,
    int* __restrict__ tok_list, int* __restrict__ slot_of, int* __restrict__ offsets) {
  __shared__ int s_cnt[E_NUM];
  __shared__ int s_base[E_NUM];
  __shared__ int s_off[E_NUM + 1];
  int tid = threadIdx.x;
  if (tid == 0) {
    int o = 0;
    for (int e2 = 0; e2 < E_NUM; ++e2) { s_off[e2] = o; o += counts[e2]; }
    s_off[E_NUM] = o;
    if (blockIdx.x == 0) {
      for (int e2 = 0; e2 <= E_NUM; ++e2) offsets[e2] = s_off[e2];
    }
  }
  if (tid < E_NUM) s_cnt[tid] = 0;
  __syncthreads();
  int t = blockIdx.x * 256 + tid;
  int e[TOPK], lslot[TOPK];
#pragma unroll
  for (int k = 0; k < TOPK; ++k) {
    e[k] = topk_i[t * TOPK + k];
    lslot[k] = atomicAdd(&s_cnt[e[k]], 1);
  }
  __syncthreads();
  if (tid < E_NUM) s_base[tid] = atomicAdd(&cursor[tid], s_cnt[tid]);
  __syncthreads();
#pragma unroll
  for (int k = 0; k < TOPK; ++k) {
    int slot = s_off[e[k]] + s_base[e[k]] + lslot[k];
    tok_list[slot] = t;
    slot_of[t * TOPK + k] = slot;
  }
}

// ---------------- fused transposes, 128x128 tiles, 16B stores in 256B runs ----------------
// W_in: 16e x (1024 x 2048): 8 r-tiles x 16 c-tiles = 128/expert -> 2048 blocks
// W_out: 16e x (1024 x 1024): 8 x 8 = 64/expert -> 1024 blocks. Total 3072.
// LDS: u32-packed bf16 pairs tile2[col][rpair]; stride 66 u32 (264B, 8B-aligned rows).
__global__ __launch_bounds__(256, 4) void transpose_fused_kernel(
    const float* __restrict__ W_in, unsigned short* __restrict__ winT,
    const float* __restrict__ W_out, unsigned short* __restrict__ woutT) {
  __shared__ unsigned int tile2[128][66];
  const int bid = blockIdx.x;
  const float* in;
  unsigned short* out;
  int C, r0, c0;
  if (bid < 2048) {
    int e = bid >> 7, rem = bid & 127;
    in  = W_in + (size_t)e * H_DIM * 2 * FF_DIM;
    out = winT + (size_t)e * H_DIM * 2 * FF_DIM;
    C = 2 * FF_DIM;
    r0 = (rem & 7) * 128;
    c0 = (rem >> 3) * 128;
  } else {
    int b = bid - 2048;
    int e = b >> 6, rem = b & 63;
    in  = W_out + (size_t)e * FF_DIM * H_DIM;
    out = woutT + (size_t)e * FF_DIM * H_DIM;
    C = H_DIM;
    r0 = (rem & 7) * 128;
    c0 = (rem >> 3) * 128;
  }
  const int t = threadIdx.x;
  const int tx = t & 31;   // float4 col group
  const int ty = t >> 5;   // 8 row-pair groups
#pragma unroll
  for (int j = 0; j < 8; ++j) {
    int rp = ty + j * 8;           // pair index 0..63
    int r = rp * 2;
    float4 v0 = *(const float4*)&in[(size_t)(r0 + r) * C + c0 + tx * 4];
    float4 v1 = *(const float4*)&in[(size_t)(r0 + r + 1) * C + c0 + tx * 4];
    tile2[tx * 4 + 0][rp] = (unsigned)f2bf(v0.x) | ((unsigned)f2bf(v1.x) << 16);
    tile2[tx * 4 + 1][rp] = (unsigned)f2bf(v0.y) | ((unsigned)f2bf(v1.y) << 16);
    tile2[tx * 4 + 2][rp] = (unsigned)f2bf(v0.z) | ((unsigned)f2bf(v1.z) << 16);
    tile2[tx * 4 + 3][rp] = (unsigned)f2bf(v0.w) | ((unsigned)f2bf(v1.w) << 16);
  }
  __syncthreads();
  const int ux = t & 15;   // 8-r chunk index
  const int uy = t >> 4;   // 16 col rows
#pragma unroll
  for (int j = 0; j < 8; ++j) {
    int c = uy + j * 16;
    uint2 d0 = *(const uint2*)&tile2[c][ux * 4];
    uint2 d1 = *(const uint2*)&tile2[c][ux * 4 + 2];
    uint4 q = make_uint4(d0.x, d0.y, d1.x, d1.y);  // r = 8ux .. 8ux+7 (LE pairs)
    *(uint4*)&out[(size_t)(c0 + c) * 1024 + r0 + ux * 8] = q;
  }
}

// ---------------- GEMM1: 128x64(panel) tile, 4 waves 64x32, 2-phase dbuf ----------------
// grid: 8192 blocks (2048 active), XCD swizzle, mt FAST.
__global__ __launch_bounds__(256, 6) void gemm1_kernel(
    const unsigned short* __restrict__ xb, const unsigned short* __restrict__ winT,
    const float* __restrict__ b_in, const int* __restrict__ offsets,
    const int* __restrict__ tok_list, unsigned short* __restrict__ act) {
  __shared__ unsigned short ldsA[2][128 * BK];
  __shared__ unsigned short ldsB[2][64 * BK];
  const int lin = blockIdx.x;
  const int nid = (lin & 7) * 1024 + (lin >> 3);
  const int e  = nid >> 9;
  const int nt = (nid >> 4) & 31;
  const int mt = nid & 15;
  const int base = offsets[e];
  const int cnt = offsets[e + 1] - base;
  if (mt * 128 >= cnt) return;
  const int n0f = nt * 32;
  const int tid = threadIdx.x, w = tid >> 6, lane = tid & 63;

  const int arow = w * 16 + (lane >> 2);
  const int t0 = tok_list[base + imin(mt * 128 + arow, cnt - 1)];
  const int t1 = tok_list[base + imin(mt * 128 + arow + 64, cnt - 1)];
  const unsigned short* gA0 = xb + (size_t)t0 * H_DIM + (lane & 3) * 8;
  const unsigned short* gA1 = xb + (size_t)t1 * H_DIM + (lane & 3) * 8;
  const int rB = arow;
  const int fB = n0f + ((rB >> 5) << 4) + (rB & 15);
  const int wrow = ((rB >> 4) & 1) ? (FF_DIM + fB) : fB;
  const unsigned short* we = winT + (size_t)e * 2 * FF_DIM * H_DIM;
  const unsigned short* gB0 = we + (size_t)wrow * H_DIM + (lane & 3) * 8;

  f32x4 acc[4][2];
#pragma unroll
  for (int m = 0; m < 4; ++m)
#pragma unroll
    for (int n = 0; n < 2; ++n) acc[m][n] = (f32x4){0.f, 0.f, 0.f, 0.f};

#define STAGE1(buf, k0)                                        \
  do {                                                         \
    gload16(gA0 + (k0), &ldsA[buf][(w * 16) * BK]);            \
    gload16(gA1 + (k0), &ldsA[buf][(w * 16 + 64) * BK]);       \
    gload16(gB0 + (k0), &ldsB[buf][(w * 16) * BK]);            \
  } while (0)

  STAGE1(0, 0);
  __syncthreads();
  int buf = 0;
  const int ko = (lane >> 4) * 8;
  const int wm = (w >> 1) * 64, wn = (w & 1) * 32;
  for (int kt = 0; kt < NT; ++kt) {
    if (kt + 1 < NT) STAGE1(buf ^ 1, (kt + 1) * BK);
    bf16x8 a[4], b[2];
#pragma unroll
    for (int mf = 0; mf < 4; ++mf)
      a[mf] = *(const bf16x8*)&ldsA[buf][(wm + mf * 16 + (lane & 15)) * BK + ko];
#pragma unroll
    for (int nf = 0; nf < 2; ++nf)
      b[nf] = *(const bf16x8*)&ldsB[buf][(wn + nf * 16 + (lane & 15)) * BK + ko];
#pragma unroll
    for (int mf = 0; mf < 4; ++mf)
#pragma unroll
      for (int nf = 0; nf < 2; ++nf)
        acc[mf][nf] = __builtin_amdgcn_mfma_f32_16x16x32_bf16(a[mf], b[nf], acc[mf][nf], 0, 0, 0);
    __syncthreads();
    buf ^= 1;
  }

  const float* bin = b_in + (size_t)e * 2 * FF_DIM;
  const int f = n0f + (w & 1) * 16 + (lane & 15);
  const float bu = bin[f], bg = bin[FF_DIM + f];
#pragma unroll
  for (int mf = 0; mf < 4; ++mf) {
    int rbase = wm + mf * 16 + (lane >> 4) * 4;
#pragma unroll
    for (int i = 0; i < 4; ++i) {
      int mrow = mt * 128 + rbase + i;
      if (mrow < cnt) {
        float up = acc[mf][0][i] + bu;
        float gt = acc[mf][1][i] + bg;
        up = fminf(fmaxf(up, -CLIPV), CLIPV);
        gt = fminf(fmaxf(gt, -CLIPV), CLIPV);
        float av = (gt / (1.f + expf(-gt))) * up;
        act[(size_t)(base + mrow) * FF_DIM + f] = f2bf(av);
      }
    }
  }
}

// ---------------- GEMM2: eo[slot] = act[slot]@W_out^T + b_out, 128x128, 2-phase ------
// grid: 2048 blocks, XCD swizzle, mt FAST. nid = e*128 + nt*16 + mt ; n0 = nt*128.
__global__ __launch_bounds__(256, 4) void gemm2_kernel(
    const unsigned short* __restrict__ act, const unsigned short* __restrict__ woutT,
    const float* __restrict__ b_out, const int* __restrict__ offsets,
    float* __restrict__ eo) {
  __shared__ unsigned short ldsA[2][128 * BK];
  __shared__ unsigned short ldsB[2][128 * BK];
  const int lin = blockIdx.x;
  const int nid = (lin & 7) * 256 + (lin >> 3);
  const int e = nid >> 7;
  const int nt = (nid >> 4) & 7;
  const int mt = nid & 15;
  const int base = offsets[e];
  const int cnt = offsets[e + 1] - base;
  if (mt * 128 >= cnt) return;
  const int n0 = nt * 128;
  const int tid = threadIdx.x, w = tid >> 6, lane = tid & 63;

  const int srow0 = w * 32 + (lane >> 2);
  const int srow1 = srow0 + 16;
  const int m0_ = imin(mt * 128 + srow0, cnt - 1);
  const int m1_ = imin(mt * 128 + srow1, cnt - 1);
  const unsigned short* gA0 = act + (size_t)(base + m0_) * FF_DIM + (lane & 3) * 8;
  const unsigned short* gA1 = act + (size_t)(base + m1_) * FF_DIM + (lane & 3) * 8;
  const unsigned short* we = woutT + (size_t)e * H_DIM * FF_DIM;
  const unsigned short* gB0 = we + (size_t)(n0 + srow0) * FF_DIM + (lane & 3) * 8;
  const unsigned short* gB1 = we + (size_t)(n0 + srow1) * FF_DIM + (lane & 3) * 8;

  f32x4 acc[4][4];
#pragma unroll
  for (int m = 0; m < 4; ++m)
#pragma unroll
    for (int n = 0; n < 4; ++n) acc[m][n] = (f32x4){0.f, 0.f, 0.f, 0.f};

#define STAGE2(buf, k0)                                        \
  do {                                                         \
    gload16(gA0 + (k0), &ldsA[buf][(w * 32 + 0) * BK]);        \
    gload16(gA1 + (k0), &ldsA[buf][(w * 32 + 16) * BK]);       \
    gload16(gB0 + (k0), &ldsB[buf][(w * 32 + 0) * BK]);        \
    gload16(gB1 + (k0), &ldsB[buf][(w * 32 + 16) * BK]);       \
  } while (0)

  STAGE2(0, 0);
  __syncthreads();
  int buf = 0;
  const int ko = (lane >> 4) * 8;
  const int wm = (w >> 1) * 64, wn = (w & 1) * 64;
  for (int kt = 0; kt < FF_DIM / BK; ++kt) {
    if (kt + 1 < FF_DIM / BK) STAGE2(buf ^ 1, (kt + 1) * BK);
    bf16x8 a[4], b[4];
#pragma unroll
    for (int mf = 0; mf < 4; ++mf)
      a[mf] = *(const bf16x8*)&ldsA[buf][(wm + mf * 16 + (lane & 15)) * BK + ko];
#pragma unroll
    for (int nf = 0; nf < 4; ++nf)
      b[nf] = *(const bf16x8*)&ldsB[buf][(wn + nf * 16 + (lane & 15)) * BK + ko];
#pragma unroll
    for (int mf = 0; mf < 4; ++mf)
#pragma unroll
      for (int nf = 0; nf < 4; ++nf)
        acc[mf][nf] = __builtin_amdgcn_mfma_f32_16x16x32_bf16(a[mf], b[nf], acc[mf][nf], 0, 0, 0);
    __syncthreads();
    buf ^= 1;
  }

  const float* bo = b_out + (size_t)e * H_DIM;
#pragma unroll
  for (int mf = 0; mf < 4; ++mf) {
#pragma unroll
    for (int i = 0; i < 4; ++i) {
      int mrow = mt * 128 + wm + mf * 16 + (lane >> 4) * 4 + i;
      if (mrow < cnt) {
        float* row = eo + (size_t)(base + mrow) * H_DIM;
#pragma unroll
        for (int nf = 0; nf < 4; ++nf) {
          int h = n0 + wn + nf * 16 + (lane & 15);
          row[h] = acc[mf][nf][i] + bo[h];
        }
      }
    }
  }
}

// ---------------- combine + aux finalize ----------------
__global__ __launch_bounds__(256) void combine_kernel(
    const float* __restrict__ eo, const float* __restrict__ topk_w,
    const int* __restrict__ slot_of, float* __restrict__ out,
    const float* __restrict__ imp, const int* __restrict__ pos_cnt) {
  int t = blockIdx.x;
  int tid = threadIdx.x;
  float4 r = make_float4(0.f, 0.f, 0.f, 0.f);
#pragma unroll
  for (int k = 0; k < TOPK; ++k) {
    int s = slot_of[t * TOPK + k];
    float wv = topk_w[t * TOPK + k];
    float4 v = ((const float4*)(eo + (size_t)s * H_DIM))[tid];
    r.x = fmaf(wv, v.x, r.x);
    r.y = fmaf(wv, v.y, r.y);
    r.z = fmaf(wv, v.z, r.z);
    r.w = fmaf(wv, v.w, r.w);
  }
  ((float4*)(out + (size_t)t * H_DIM))[tid] = r;
  if (t == 0 && tid == 0) {
    float s = 0.f;
    for (int p = 0; p < TOPK; ++p)
      s += (imp[p] / (float)S_TOK) * ((float)pos_cnt[p] / (float)S_TOK);
    out[(size_t)S_TOK * H_DIM] = AUXC * (float)E_NUM * s;
  }
}

extern "C" void kernel_launch(void* const* d_in, const int* in_sizes, int n_in,
                              void* d_out, int out_size, void* d_ws, size_t ws_size,
                              hipStream_t stream) {
  const float* x     = (const float*)d_in[0];
  const float* W_in  = (const float*)d_in[1];
  const float* b_in  = (const float*)d_in[2];
  const float* W_out = (const float*)d_in[3];
  const float* b_out = (const float*)d_in[4];
  const float* rw    = (const float*)d_in[5];
  const float* rb    = (const float*)d_in[6];
  float* out = (float*)d_out;

  char* ws = (char*)d_ws;
  size_t off = 0;
  auto alloc = [&](size_t bytes) {
    void* p = ws + off;
    off = (off + bytes + 255) & ~(size_t)255;
    return p;
  };
  unsigned short* xb    = (unsigned short*)alloc((size_t)S_TOK * H_DIM * 2);
  unsigned short* winT  = (unsigned short*)alloc((size_t)E_NUM * 2 * FF_DIM * H_DIM * 2);
  unsigned short* woutT = (unsigned short*)alloc((size_t)E_NUM * H_DIM * FF_DIM * 2);
  unsigned short* act   = (unsigned short*)alloc((size_t)S_TOK * TOPK * FF_DIM * 2);
  float* eo      = (float*)alloc((size_t)S_TOK * TOPK * H_DIM * 4);
  float* logits  = (float*)alloc((size_t)S_TOK * E_NUM * 4);
  int*   topk_i  = (int*)alloc(S_TOK * TOPK * 4);
  float* topk_w  = (float*)alloc(S_TOK * TOPK * 4);
  int*   tok_list= (int*)alloc(S_TOK * TOPK * 4);
  int*   slot_of = (int*)alloc(S_TOK * TOPK * 4);
  int* ctrl = (int*)alloc(64 * 4);
  int* counts = ctrl;
  int* cursor = ctrl + 16;
  int* pos_cnt = ctrl + 32;
  float* imp = (float*)(ctrl + 48);
  int* offsets = (int*)alloc(32 * 4);

  hipMemsetAsync(ctrl, 0, 64 * 4, stream);

  transpose_fused_kernel<<<3072, 256, 0, stream>>>(W_in, winT, W_out, woutT);
  logits_kernel<<<S_TOK / 4, 256, 0, stream>>>(x, rw, rb, logits, xb);
  topk_kernel<<<S_TOK / 256, 256, 0, stream>>>(logits, topk_i, topk_w, counts, imp, pos_cnt);
  assign_kernel<<<S_TOK / 256, 256, 0, stream>>>(topk_i, counts, cursor, tok_list, slot_of, offsets);
  gemm1_kernel<<<8192, 256, 0, stream>>>(xb, winT, b_in, offsets, tok_list, act);
  gemm2_kernel<<<2048, 256, 0, stream>>>(act, woutT, b_out, offsets, eo);
  combine_kernel<<<S_TOK, 256, 0, stream>>>(eo, topk_w, slot_of, out, imp, pos_cnt);
}

// Round 14
// 200.468 us; speedup vs baseline: 1.0037x; 1.0037x over previous
//
#include <hip/hip_runtime.h>
#include <math.h>

#define S_TOK 2048
#define H_DIM 1024
#define E_NUM 16
#define FF_DIM 1024
#define TOPK 4
#define CLIPV 7.0f
#define AUXC 0.02f
#define BK 32
#define NT (H_DIM / BK)

typedef short bf16x8 __attribute__((ext_vector_type(8)));
typedef float f32x4 __attribute__((ext_vector_type(4)));

__device__ __forceinline__ unsigned short f2bf(float f) {
  unsigned int u = __float_as_uint(f);
  u += 0x7fffu + ((u >> 16) & 1u);
  return (unsigned short)(u >> 16);
}

__device__ __forceinline__ void gload16(const void* g, void* l) {
  __builtin_amdgcn_global_load_lds((const __attribute__((address_space(1))) void*)g,
                                   (__attribute__((address_space(3))) void*)l, 16, 0, 0);
}

__device__ __forceinline__ int imin(int a, int b) { return a < b ? a : b; }

// ---------------- router logits + x->bf16 convert: one wave per token ----------------
__global__ void logits_kernel(const float* __restrict__ x, const float* __restrict__ rw,
                              const float* __restrict__ rb, float* __restrict__ logits,
                              unsigned short* __restrict__ xb) {
  int tok = blockIdx.x * 4 + (threadIdx.x >> 6);
  int lane = threadIdx.x & 63;
  const float4* xr = (const float4*)(x + (size_t)tok * H_DIM);
  ushort4* xbw = (ushort4*)(xb + (size_t)tok * H_DIM);
  float p[E_NUM];
#pragma unroll
  for (int e = 0; e < E_NUM; ++e) p[e] = 0.f;
#pragma unroll
  for (int it = 0; it < 4; ++it) {
    float4 xv = xr[it * 64 + lane];
    ushort4 o;
    o.x = f2bf(xv.x); o.y = f2bf(xv.y); o.z = f2bf(xv.z); o.w = f2bf(xv.w);
    xbw[it * 64 + lane] = o;
#pragma unroll
    for (int e = 0; e < E_NUM; ++e) {
      float4 wv = ((const float4*)(rw + (size_t)e * H_DIM))[it * 64 + lane];
      p[e] += xv.x * wv.x + xv.y * wv.y + xv.z * wv.z + xv.w * wv.w;
    }
  }
#pragma unroll
  for (int e = 0; e < E_NUM; ++e) {
#pragma unroll
    for (int off = 32; off > 0; off >>= 1) p[e] += __shfl_xor(p[e], off);
  }
  if (lane == 0) {
    float4* lp = (float4*)&logits[tok * E_NUM];
#pragma unroll
    for (int q = 0; q < 4; ++q)
      lp[q] = make_float4(p[q * 4 + 0] + rb[q * 4 + 0], p[q * 4 + 1] + rb[q * 4 + 1],
                          p[q * 4 + 2] + rb[q * 4 + 2], p[q * 4 + 3] + rb[q * 4 + 3]);
  }
}

// ---------------- top-k + aux stats ----------------
__global__ __launch_bounds__(256) void topk_kernel(const float* __restrict__ logits,
                                                   int* __restrict__ topk_i, float* __restrict__ topk_w,
                                                   int* __restrict__ counts, float* __restrict__ imp,
                                                   int* __restrict__ pos_cnt) {
  __shared__ float s_imp[E_NUM];
  __shared__ int s_cnt[E_NUM];
  __shared__ int s_pos[TOPK];
  int tid = threadIdx.x;
  if (tid < E_NUM) { s_imp[tid] = 0.f; s_cnt[tid] = 0; }
  if (tid < TOPK) s_pos[tid] = 0;
  __syncthreads();

  int t = blockIdx.x * 256 + tid;
  float lg[E_NUM];
  {
    const float4* lp = (const float4*)&logits[t * E_NUM];
#pragma unroll
    for (int q = 0; q < 4; ++q) {
      float4 v = lp[q];
      lg[q * 4 + 0] = v.x; lg[q * 4 + 1] = v.y; lg[q * 4 + 2] = v.z; lg[q * 4 + 3] = v.w;
    }
  }
  int idx[TOPK]; float val[TOPK];
  float tmp[E_NUM];
#pragma unroll
  for (int e = 0; e < E_NUM; ++e) tmp[e] = lg[e];
#pragma unroll
  for (int k = 0; k < TOPK; ++k) {
    float best = -INFINITY; int bi = 0;
#pragma unroll
    for (int e = 0; e < E_NUM; ++e) if (tmp[e] > best) { best = tmp[e]; bi = e; }
    val[k] = best; idx[k] = bi; tmp[bi] = -INFINITY;
  }
  float ssum = 0.f, wv[TOPK];
#pragma unroll
  for (int k = 0; k < TOPK; ++k) { wv[k] = expf(val[k] - val[0]); ssum += wv[k]; }
#pragma unroll
  for (int k = 0; k < TOPK; ++k) wv[k] /= ssum;
#pragma unroll
  for (int k = 0; k < TOPK; ++k) {
    topk_i[t * TOPK + k] = idx[k];
    topk_w[t * TOPK + k] = wv[k];
  }
  float se = 0.f, pr[E_NUM];
#pragma unroll
  for (int e = 0; e < E_NUM; ++e) { pr[e] = expf(lg[e] - val[0]); se += pr[e]; }
  float inv = 1.f / se;
  int mi = idx[0], pos = 0;
#pragma unroll
  for (int k = 1; k < TOPK; ++k) if (idx[k] > mi) { mi = idx[k]; pos = k; }

  int lane = tid & 63;
#pragma unroll
  for (int e = 0; e < E_NUM; ++e) {
    float v = pr[e] * inv;
    int c = (idx[0] == e) + (idx[1] == e) + (idx[2] == e) + (idx[3] == e);
#pragma unroll
    for (int off = 32; off > 0; off >>= 1) {
      v += __shfl_xor(v, off);
      c += __shfl_xor(c, off);
    }
    if (lane == 0) {
      atomicAdd(&s_imp[e], v);
      atomicAdd(&s_cnt[e], c);
    }
  }
#pragma unroll
  for (int k = 0; k < TOPK; ++k) {
    int pc = (pos == k) ? 1 : 0;
#pragma unroll
    for (int off = 32; off > 0; off >>= 1) pc += __shfl_xor(pc, off);
    if (lane == 0) atomicAdd(&s_pos[k], pc);
  }
  __syncthreads();
  if (tid < E_NUM) {
    atomicAdd(&imp[tid], s_imp[tid]);
    atomicAdd(&counts[tid], s_cnt[tid]);
  }
  if (tid < TOPK) atomicAdd(&pos_cnt[tid], s_pos[tid]);
}

// ---------------- build grouped token lists + inverse slot map (scan folded in) ----------------
__global__ __launch_bounds__(256) void assign_kernel(
    const int* __restrict__ topk_i, const int* __restrict__ counts, int* __restrict__ cursor,
    int* __restrict__ tok_list, int* __restrict__ slot_of, int* __restrict__ offsets) {
  __shared__ int s_cnt[E_NUM];
  __shared__ int s_base[E_NUM];
  __shared__ int s_off[E_NUM + 1];
  int tid = threadIdx.x;
  if (tid == 0) {
    int o = 0;
    for (int e2 = 0; e2 < E_NUM; ++e2) { s_off[e2] = o; o += counts[e2]; }
    s_off[E_NUM] = o;
    if (blockIdx.x == 0) {
      for (int e2 = 0; e2 <= E_NUM; ++e2) offsets[e2] = s_off[e2];
    }
  }
  if (tid < E_NUM) s_cnt[tid] = 0;
  __syncthreads();
  int t = blockIdx.x * 256 + tid;
  int e[TOPK], lslot[TOPK];
#pragma unroll
  for (int k = 0; k < TOPK; ++k) {
    e[k] = topk_i[t * TOPK + k];
    lslot[k] = atomicAdd(&s_cnt[e[k]], 1);
  }
  __syncthreads();
  if (tid < E_NUM) s_base[tid] = atomicAdd(&cursor[tid], s_cnt[tid]);
  __syncthreads();
#pragma unroll
  for (int k = 0; k < TOPK; ++k) {
    int slot = s_off[e[k]] + s_base[e[k]] + lslot[k];
    tok_list[slot] = t;
    slot_of[t * TOPK + k] = slot;
  }
}

// ---------------- fused transposes (R12-exact, passing), 128x128 tiles ----------------
__global__ __launch_bounds__(256, 4) void transpose_fused_kernel(
    const float* __restrict__ W_in, unsigned short* __restrict__ winT,
    const float* __restrict__ W_out, unsigned short* __restrict__ woutT) {
  __shared__ unsigned int tile2[128][66];
  const int bid = blockIdx.x;
  const float* in;
  unsigned short* out;
  int C, r0, c0;
  if (bid < 2048) {
    int e = bid >> 7, rem = bid & 127;
    in  = W_in + (size_t)e * H_DIM * 2 * FF_DIM;
    out = winT + (size_t)e * H_DIM * 2 * FF_DIM;
    C = 2 * FF_DIM;
    r0 = (rem & 7) * 128;
    c0 = (rem >> 3) * 128;
  } else {
    int b = bid - 2048;
    int e = b >> 6, rem = b & 63;
    in  = W_out + (size_t)e * FF_DIM * H_DIM;
    out = woutT + (size_t)e * FF_DIM * H_DIM;
    C = H_DIM;
    r0 = (rem & 7) * 128;
    c0 = (rem >> 3) * 128;
  }
  const int t = threadIdx.x;
  const int tx = t & 31;   // float4 col group
  const int ty = t >> 5;   // 8 row-pair groups
#pragma unroll
  for (int j = 0; j < 8; ++j) {
    int rp = ty + j * 8;           // pair index 0..63
    int r = rp * 2;
    float4 v0 = *(const float4*)&in[(size_t)(r0 + r) * C + c0 + tx * 4];
    float4 v1 = *(const float4*)&in[(size_t)(r0 + r + 1) * C + c0 + tx * 4];
    tile2[tx * 4 + 0][rp] = (unsigned)f2bf(v0.x) | ((unsigned)f2bf(v1.x) << 16);
    tile2[tx * 4 + 1][rp] = (unsigned)f2bf(v0.y) | ((unsigned)f2bf(v1.y) << 16);
    tile2[tx * 4 + 2][rp] = (unsigned)f2bf(v0.z) | ((unsigned)f2bf(v1.z) << 16);
    tile2[tx * 4 + 3][rp] = (unsigned)f2bf(v0.w) | ((unsigned)f2bf(v1.w) << 16);
  }
  __syncthreads();
  const int ux = t & 15;   // 8-r chunk index
  const int uy = t >> 4;   // 16 col rows
#pragma unroll
  for (int j = 0; j < 8; ++j) {
    int c = uy + j * 16;
    uint2 d0 = *(const uint2*)&tile2[c][ux * 4];
    uint2 d1 = *(const uint2*)&tile2[c][ux * 4 + 2];
    uint4 q = make_uint4(d0.x, d0.y, d1.x, d1.y);
    *(uint4*)&out[(size_t)(c0 + c) * 1024 + r0 + ux * 8] = q;
  }
}

// ---------------- GEMM1: 128x64(panel), 4 waves 64x32, 2-phase dbuf + T2 swizzle ----------
// Swizzle (R9-verified pair): source chunk csrc=(l&3)^((l>>3)&3) (linear gload_lds dest),
// read chunk kos=((l>>4)^((l>>1)&3))*8. grid: 8192 blocks, XCD swizzle, mt FAST.
__global__ __launch_bounds__(256, 6) void gemm1_kernel(
    const unsigned short* __restrict__ xb, const unsigned short* __restrict__ winT,
    const float* __restrict__ b_in, const int* __restrict__ offsets,
    const int* __restrict__ tok_list, unsigned short* __restrict__ act) {
  __shared__ unsigned short ldsA[2][128 * BK];
  __shared__ unsigned short ldsB[2][64 * BK];
  const int lin = blockIdx.x;
  const int nid = (lin & 7) * 1024 + (lin >> 3);
  const int e  = nid >> 9;
  const int nt = (nid >> 4) & 31;
  const int mt = nid & 15;
  const int base = offsets[e];
  const int cnt = offsets[e + 1] - base;
  if (mt * 128 >= cnt) return;
  const int n0f = nt * 32;
  const int tid = threadIdx.x, w = tid >> 6, lane = tid & 63;

  const int csrc = (lane & 3) ^ ((lane >> 3) & 3);
  const int arow = w * 16 + (lane >> 2);
  const int t0 = tok_list[base + imin(mt * 128 + arow, cnt - 1)];
  const int t1 = tok_list[base + imin(mt * 128 + arow + 64, cnt - 1)];
  const unsigned short* gA0 = xb + (size_t)t0 * H_DIM + csrc * 8;
  const unsigned short* gA1 = xb + (size_t)t1 * H_DIM + csrc * 8;
  const int rB = arow;
  const int fB = n0f + ((rB >> 5) << 4) + (rB & 15);
  const int wrow = ((rB >> 4) & 1) ? (FF_DIM + fB) : fB;
  const unsigned short* we = winT + (size_t)e * 2 * FF_DIM * H_DIM;
  const unsigned short* gB0 = we + (size_t)wrow * H_DIM + csrc * 8;

  f32x4 acc[4][2];
#pragma unroll
  for (int m = 0; m < 4; ++m)
#pragma unroll
    for (int n = 0; n < 2; ++n) acc[m][n] = (f32x4){0.f, 0.f, 0.f, 0.f};

#define STAGE1(buf, k0)                                        \
  do {                                                         \
    gload16(gA0 + (k0), &ldsA[buf][(w * 16) * BK]);            \
    gload16(gA1 + (k0), &ldsA[buf][(w * 16 + 64) * BK]);       \
    gload16(gB0 + (k0), &ldsB[buf][(w * 16) * BK]);            \
  } while (0)

  STAGE1(0, 0);
  __syncthreads();
  int buf = 0;
  const int kos = (((lane >> 4) ^ ((lane >> 1) & 3)) * 8);
  const int wm = (w >> 1) * 64, wn = (w & 1) * 32;
  for (int kt = 0; kt < NT; ++kt) {
    if (kt + 1 < NT) STAGE1(buf ^ 1, (kt + 1) * BK);
    bf16x8 a[4], b[2];
#pragma unroll
    for (int mf = 0; mf < 4; ++mf)
      a[mf] = *(const bf16x8*)&ldsA[buf][(wm + mf * 16 + (lane & 15)) * BK + kos];
#pragma unroll
    for (int nf = 0; nf < 2; ++nf)
      b[nf] = *(const bf16x8*)&ldsB[buf][(wn + nf * 16 + (lane & 15)) * BK + kos];
#pragma unroll
    for (int mf = 0; mf < 4; ++mf)
#pragma unroll
      for (int nf = 0; nf < 2; ++nf)
        acc[mf][nf] = __builtin_amdgcn_mfma_f32_16x16x32_bf16(a[mf], b[nf], acc[mf][nf], 0, 0, 0);
    __syncthreads();
    buf ^= 1;
  }

  const float* bin = b_in + (size_t)e * 2 * FF_DIM;
  const int f = n0f + (w & 1) * 16 + (lane & 15);
  const float bu = bin[f], bg = bin[FF_DIM + f];
#pragma unroll
  for (int mf = 0; mf < 4; ++mf) {
    int rbase = wm + mf * 16 + (lane >> 4) * 4;
#pragma unroll
    for (int i = 0; i < 4; ++i) {
      int mrow = mt * 128 + rbase + i;
      if (mrow < cnt) {
        float up = acc[mf][0][i] + bu;
        float gt = acc[mf][1][i] + bg;
        up = fminf(fmaxf(up, -CLIPV), CLIPV);
        gt = fminf(fmaxf(gt, -CLIPV), CLIPV);
        float av = (gt / (1.f + expf(-gt))) * up;
        act[(size_t)(base + mrow) * FF_DIM + f] = f2bf(av);
      }
    }
  }
}

// ---------------- GEMM2: eo[slot] = act[slot]@W_out^T + b_out, 128x128, 2-phase + T2 ------
// grid: 2048 blocks, XCD swizzle, mt FAST. nid = e*128 + nt*16 + mt ; n0 = nt*128.
__global__ __launch_bounds__(256, 4) void gemm2_kernel(
    const unsigned short* __restrict__ act, const unsigned short* __restrict__ woutT,
    const float* __restrict__ b_out, const int* __restrict__ offsets,
    float* __restrict__ eo) {
  __shared__ unsigned short ldsA[2][128 * BK];
  __shared__ unsigned short ldsB[2][128 * BK];
  const int lin = blockIdx.x;
  const int nid = (lin & 7) * 256 + (lin >> 3);
  const int e = nid >> 7;
  const int nt = (nid >> 4) & 7;
  const int mt = nid & 15;
  const int base = offsets[e];
  const int cnt = offsets[e + 1] - base;
  if (mt * 128 >= cnt) return;
  const int n0 = nt * 128;
  const int tid = threadIdx.x, w = tid >> 6, lane = tid & 63;

  const int csrc = (lane & 3) ^ ((lane >> 3) & 3);
  const int srow0 = w * 32 + (lane >> 2);
  const int srow1 = srow0 + 16;
  const int m0_ = imin(mt * 128 + srow0, cnt - 1);
  const int m1_ = imin(mt * 128 + srow1, cnt - 1);
  const unsigned short* gA0 = act + (size_t)(base + m0_) * FF_DIM + csrc * 8;
  const unsigned short* gA1 = act + (size_t)(base + m1_) * FF_DIM + csrc * 8;
  const unsigned short* we = woutT + (size_t)e * H_DIM * FF_DIM;
  const unsigned short* gB0 = we + (size_t)(n0 + srow0) * FF_DIM + csrc * 8;
  const unsigned short* gB1 = we + (size_t)(n0 + srow1) * FF_DIM + csrc * 8;

  f32x4 acc[4][4];
#pragma unroll
  for (int m = 0; m < 4; ++m)
#pragma unroll
    for (int n = 0; n < 4; ++n) acc[m][n] = (f32x4){0.f, 0.f, 0.f, 0.f};

#define STAGE2(buf, k0)                                        \
  do {                                                         \
    gload16(gA0 + (k0), &ldsA[buf][(w * 32 + 0) * BK]);        \
    gload16(gA1 + (k0), &ldsA[buf][(w * 32 + 16) * BK]);       \
    gload16(gB0 + (k0), &ldsB[buf][(w * 32 + 0) * BK]);        \
    gload16(gB1 + (k0), &ldsB[buf][(w * 32 + 16) * BK]);       \
  } while (0)

  STAGE2(0, 0);
  __syncthreads();
  int buf = 0;
  const int kos = (((lane >> 4) ^ ((lane >> 1) & 3)) * 8);
  const int wm = (w >> 1) * 64, wn = (w & 1) * 64;
  for (int kt = 0; kt < FF_DIM / BK; ++kt) {
    if (kt + 1 < FF_DIM / BK) STAGE2(buf ^ 1, (kt + 1) * BK);
    bf16x8 a[4], b[4];
#pragma unroll
    for (int mf = 0; mf < 4; ++mf)
      a[mf] = *(const bf16x8*)&ldsA[buf][(wm + mf * 16 + (lane & 15)) * BK + kos];
#pragma unroll
    for (int nf = 0; nf < 4; ++nf)
      b[nf] = *(const bf16x8*)&ldsB[buf][(wn + nf * 16 + (lane & 15)) * BK + kos];
#pragma unroll
    for (int mf = 0; mf < 4; ++mf)
#pragma unroll
      for (int nf = 0; nf < 4; ++nf)
        acc[mf][nf] = __builtin_amdgcn_mfma_f32_16x16x32_bf16(a[mf], b[nf], acc[mf][nf], 0, 0, 0);
    __syncthreads();
    buf ^= 1;
  }

  const float* bo = b_out + (size_t)e * H_DIM;
#pragma unroll
  for (int mf = 0; mf < 4; ++mf) {
#pragma unroll
    for (int i = 0; i < 4; ++i) {
      int mrow = mt * 128 + wm + mf * 16 + (lane >> 4) * 4 + i;
      if (mrow < cnt) {
        float* row = eo + (size_t)(base + mrow) * H_DIM;
#pragma unroll
        for (int nf = 0; nf < 4; ++nf) {
          int h = n0 + wn + nf * 16 + (lane & 15);
          row[h] = acc[mf][nf][i] + bo[h];
        }
      }
    }
  }
}

// ---------------- combine + aux finalize ----------------
__global__ __launch_bounds__(256) void combine_kernel(
    const float* __restrict__ eo, const float* __restrict__ topk_w,
    const int* __restrict__ slot_of, float* __restrict__ out,
    const float* __restrict__ imp, const int* __restrict__ pos_cnt) {
  int t = blockIdx.x;
  int tid = threadIdx.x;
  float4 r = make_float4(0.f, 0.f, 0.f, 0.f);
#pragma unroll
  for (int k = 0; k < TOPK; ++k) {
    int s = slot_of[t * TOPK + k];
    float wv = topk_w[t * TOPK + k];
    float4 v = ((const float4*)(eo + (size_t)s * H_DIM))[tid];
    r.x = fmaf(wv, v.x, r.x);
    r.y = fmaf(wv, v.y, r.y);
    r.z = fmaf(wv, v.z, r.z);
    r.w = fmaf(wv, v.w, r.w);
  }
  ((float4*)(out + (size_t)t * H_DIM))[tid] = r;
  if (t == 0 && tid == 0) {
    float s = 0.f;
    for (int p = 0; p < TOPK; ++p)
      s += (imp[p] / (float)S_TOK) * ((float)pos_cnt[p] / (float)S_TOK);
    out[(size_t)S_TOK * H_DIM] = AUXC * (float)E_NUM * s;
  }
}

extern "C" void kernel_launch(void* const* d_in, const int* in_sizes, int n_in,
                              void* d_out, int out_size, void* d_ws, size_t ws_size,
                              hipStream_t stream) {
  const float* x     = (const float*)d_in[0];
  const float* W_in  = (const float*)d_in[1];
  const float* b_in  = (const float*)d_in[2];
  const float* W_out = (const float*)d_in[3];
  const float* b_out = (const float*)d_in[4];
  const float* rw    = (const float*)d_in[5];
  const float* rb    = (const float*)d_in[6];
  float* out = (float*)d_out;

  char* ws = (char*)d_ws;
  size_t off = 0;
  auto alloc = [&](size_t bytes) {
    void* p = ws + off;
    off = (off + bytes + 255) & ~(size_t)255;
    return p;
  };
  unsigned short* xb    = (unsigned short*)alloc((size_t)S_TOK * H_DIM * 2);
  unsigned short* winT  = (unsigned short*)alloc((size_t)E_NUM * 2 * FF_DIM * H_DIM * 2);
  unsigned short* woutT = (unsigned short*)alloc((size_t)E_NUM * H_DIM * FF_DIM * 2);
  unsigned short* act   = (unsigned short*)alloc((size_t)S_TOK * TOPK * FF_DIM * 2);
  float* eo      = (float*)alloc((size_t)S_TOK * TOPK * H_DIM * 4);
  float* logits  = (float*)alloc((size_t)S_TOK * E_NUM * 4);
  int*   topk_i  = (int*)alloc(S_TOK * TOPK * 4);
  float* topk_w  = (float*)alloc(S_TOK * TOPK * 4);
  int*   tok_list= (int*)alloc(S_TOK * TOPK * 4);
  int*   slot_of = (int*)alloc(S_TOK * TOPK * 4);
  int* ctrl = (int*)alloc(64 * 4);
  int* counts = ctrl;
  int* cursor = ctrl + 16;
  int* pos_cnt = ctrl + 32;
  float* imp = (float*)(ctrl + 48);
  int* offsets = (int*)alloc(32 * 4);

  hipMemsetAsync(ctrl, 0, 64 * 4, stream);

  transpose_fused_kernel<<<3072, 256, 0, stream>>>(W_in, winT, W_out, woutT);
  logits_kernel<<<S_TOK / 4, 256, 0, stream>>>(x, rw, rb, logits, xb);
  topk_kernel<<<S_TOK / 256, 256, 0, stream>>>(logits, topk_i, topk_w, counts, imp, pos_cnt);
  assign_kernel<<<S_TOK / 256, 256, 0, stream>>>(topk_i, counts, cursor, tok_list, slot_of, offsets);
  gemm1_kernel<<<8192, 256, 0, stream>>>(xb, winT, b_in, offsets, tok_list, act);
  gemm2_kernel<<<2048, 256, 0, stream>>>(act, woutT, b_out, offsets, eo);
  combine_kernel<<<S_TOK, 256, 0, stream>>>(eo, topk_w, slot_of, out, imp, pos_cnt);
}